// Round 2
// baseline (890.418 us; speedup 1.0000x reference)
//
#include <hip/hip_runtime.h>
#include <hip/hip_bf16.h>
#include <cstdint>
#include <cstddef>

#define NH   16
#define DHD  64
#define DM   1024
#define BSZ  8
#define SEQ  4096
#define NTOK (BSZ*SEQ)      // 32768 tokens
#define NQKV (3*NH*DHD)     // 3072

typedef __attribute__((ext_vector_type(8))) __bf16 bf16x8;
typedef __attribute__((ext_vector_type(4))) float  floatx4;

// ---- helpers ----
static __device__ __forceinline__ unsigned short f2bf(float f) {
    unsigned int u = __float_as_uint(f);
    u += 0x7fffu + ((u >> 16) & 1u);   // RNE
    return (unsigned short)(u >> 16);
}
static __device__ __forceinline__ float bf2f(unsigned int us) {
    return __uint_as_float(us << 16);
}
static __device__ __forceinline__ void load_lds16(const void* g, void* l) {
    __builtin_amdgcn_global_load_lds((__attribute__((address_space(1))) void*)g,
                                     (__attribute__((address_space(3))) void*)l,
                                     16, 0, 0);
}
#define SCHED_FENCE() __builtin_amdgcn_sched_barrier(0)

// ---- cast fp32 -> bf16 (vectorized, exact multiple of 4) ----
__global__ __launch_bounds__(256) void k_cast_bf16(const float* __restrict__ in,
                                                   unsigned short* __restrict__ out, int n4) {
    int i = blockIdx.x * 256 + threadIdx.x;
    if (i >= n4) return;
    float4 v = ((const float4*)in)[i];
    ushort4 o;
    o.x = f2bf(v.x); o.y = f2bf(v.y); o.z = f2bf(v.z); o.w = f2bf(v.w);
    ((ushort4*)out)[i] = o;
}

// ---- transpose + cast: in fp32 [R][C] -> out bf16 [C][R] ----
template<int R, int C>
__global__ __launch_bounds__(256) void k_transpose_cast(const float* __restrict__ in,
                                                        unsigned short* __restrict__ out) {
    __shared__ float tile[32][33];
    int tx = threadIdx.x, ty = threadIdx.y;    // (32, 8)
    int col = blockIdx.x * 32 + tx;
#pragma unroll
    for (int k = 0; k < 4; k++) {
        int row = blockIdx.y * 32 + ty + k * 8;
        tile[ty + k * 8][tx] = in[(size_t)row * C + col];
    }
    __syncthreads();
#pragma unroll
    for (int k = 0; k < 4; k++) {
        int ocol = blockIdx.x * 32 + ty + k * 8;   // original col -> out row
        int orow = blockIdx.y * 32 + tx;           // original row -> out col
        out[(size_t)ocol * R + orow] = f2bf(tile[tx][ty + k * 8]);
    }
}

// ---- positional encoding table fp32 [4096][64] ----
__global__ __launch_bounds__(256) void k_pe(float* __restrict__ pe) {
    int t = blockIdx.x * 256 + threadIdx.x;   // 4096*32
    int l = t >> 5, i = t & 31;
    float dv = expf(-0.14391156831212787f * (float)(2 * i));
    float ang = (float)l * dv;
    pe[l * 64 + 2 * i]     = sinf(ang);
    pe[l * 64 + 2 * i + 1] = cosf(ang);
}

// ============================================================================
// m97-style 2-phase 128x128 bf16 GEMM (proven baseline) -- used for GEMM2.
// ============================================================================
template<int N, int EPI>
__global__ __launch_bounds__(256) void k_gemm(const unsigned short* __restrict__ A,
                                              const unsigned short* __restrict__ BT,
                                              const float* __restrict__ bias,
                                              const float* __restrict__ pe,
                                              void* __restrict__ Cout) {
    constexpr int K = 1024;
    __shared__ __align__(16) short lds[8192];   // As[128][32] + Bs[128][32] bf16
    short* As = lds;
    short* Bs = lds + 4096;

    int tid  = threadIdx.x;
    int lane = tid & 63;
    int wid  = tid >> 6;
    int m0 = blockIdx.y * 128;
    int n0 = blockIdx.x * 128;
    int wr = wid >> 1, wc = wid & 1;
    int l15 = lane & 15;
    int kq  = (lane >> 4) * 8;

    floatx4 acc[4][4];
#pragma unroll
    for (int i = 0; i < 4; i++)
#pragma unroll
        for (int j = 0; j < 4; j++) acc[i][j] = (floatx4){0.f, 0.f, 0.f, 0.f};

    int ci0 = wid * 128 + lane;
    int ci1 = ci0 + 64;
    const unsigned short* pa0 = A  + (size_t)(m0 + (ci0 >> 2)) * K + (ci0 & 3) * 8;
    const unsigned short* pa1 = A  + (size_t)(m0 + (ci1 >> 2)) * K + (ci1 & 3) * 8;
    const unsigned short* pb0 = BT + (size_t)(n0 + (ci0 >> 2)) * K + (ci0 & 3) * 8;
    const unsigned short* pb1 = BT + (size_t)(n0 + (ci1 >> 2)) * K + (ci1 & 3) * 8;
    short* la0 = As + ci0 * 8;
    short* la1 = As + ci1 * 8;
    short* lb0 = Bs + ci0 * 8;
    short* lb1 = Bs + ci1 * 8;

    for (int kb = 0; kb < K; kb += 32) {
        __syncthreads();
        load_lds16(pa0 + kb, la0);
        load_lds16(pa1 + kb, la1);
        load_lds16(pb0 + kb, lb0);
        load_lds16(pb1 + kb, lb1);
        __syncthreads();

        bf16x8 aF[4], bF[4];
#pragma unroll
        for (int i = 0; i < 4; i++)
            aF[i] = *(const bf16x8*)&As[(wr * 64 + i * 16 + l15) * 32 + kq];
#pragma unroll
        for (int j = 0; j < 4; j++)
            bF[j] = *(const bf16x8*)&Bs[(wc * 64 + j * 16 + l15) * 32 + kq];
#pragma unroll
        for (int i = 0; i < 4; i++)
#pragma unroll
            for (int j = 0; j < 4; j++)
                acc[i][j] = __builtin_amdgcn_mfma_f32_16x16x32_bf16(aF[i], bF[j], acc[i][j], 0, 0, 0);
    }

    int rbase = (lane >> 4) * 4;
#pragma unroll
    for (int j = 0; j < 4; j++) {
        int col = n0 + wc * 64 + j * 16 + l15;
        float bv = bias[col];
        int h = 0, rc = 0;
        if (EPI == 1) { h = col / 192; rc = col - h * 192; }
#pragma unroll
        for (int i = 0; i < 4; i++) {
#pragma unroll
            for (int r = 0; r < 4; r++) {
                int row = m0 + wr * 64 + i * 16 + rbase + r;
                float v = acc[i][j][r] + bv;
                if (EPI == 1) {
                    if (rc < 64)        v *= 0.125f;
                    else if (rc < 128)  v += pe[(row & (SEQ - 1)) * 64 + (rc - 64)];
                    ((unsigned short*)Cout)[(size_t)row * N + col] = f2bf(v);
                } else {
                    ((float*)Cout)[(size_t)row * N + col] = v;
                }
            }
        }
    }
}

// ============================================================================
// 256x256-tile 8-phase bf16 GEMM, K = 1024, BK = 64 -- GEMM1.
// Round-2 change vs round-1: __builtin_amdgcn_sched_barrier(0) pins at phase
// boundaries (rule 18): (a) after ds_read+STAGE issue block -- stops the
// compiler sinking LDS reads past s_barrier (IntrNoMem!) into the MFMA
// region, which serialized reads with MFMA; (b) after the waitcnt asm --
// stops MFMA hoisting above the wait; (c) after setprio(0) -- stops
// next-phase reads hoisting above the vmcnt guard.
// ============================================================================
template<int N, int EPI>
__global__ __launch_bounds__(512, 2) void k_gemm8(const unsigned short* __restrict__ A,
                                                  const unsigned short* __restrict__ BT,
                                                  const float* __restrict__ bias,
                                                  const float* __restrict__ pe,
                                                  void* __restrict__ Cout) {
    constexpr int K   = 1024;
    constexpr int NKT = K / 64;          // 16 K-tiles
    constexpr int NIT = NKT / 2;         // 8 iterations
    constexpr int NBX = N / 256;
    constexpr int nwg = NBX * (NTOK / 256);

    __shared__ __align__(16) short sh[65536];   // 128 KiB
    char* shb = (char*)sh;

    const int tid  = threadIdx.x;
    const int lane = tid & 63;
    const int wid  = tid >> 6;
    const int l15  = lane & 15;
    const int q4   = lane >> 4;
    const int wr   = wid >> 2;           // 0..1 (M)
    const int wc   = wid & 3;            // 0..3 (N)

    const int id = blockIdx.x;
    const int sw = (id & 7) * (nwg >> 3) + (id >> 3);
    const int m0 = (sw / NBX) * 256;
    const int n0 = (sw % NBX) * 256;

    int cj[2];
    const unsigned short* srcA[2];
    const unsigned short* srcB[2];
#pragma unroll
    for (int j = 0; j < 2; j++) {
        int c  = wid * 128 + j * 64 + lane;
        cj[j]  = c;
        int rh = c >> 3;
        int sl = (c & 7) ^ (rh & 7);
        srcA[j] = A  + (size_t)(m0 + rh) * K + sl * 8;
        srcB[j] = BT + (size_t)(n0 + rh) * K + sl * 8;
    }
    auto STAGE_A = [&](int kt, int half) {
#pragma unroll
        for (int j = 0; j < 2; j++)
            load_lds16(srcA[j] + half * 128 * K + kt * 64,
                       shb + (kt & 1) * 32768 + half * 16384 + cj[j] * 16);
    };
    auto STAGE_B = [&](int kt, int half) {
#pragma unroll
        for (int j = 0; j < 2; j++)
            load_lds16(srcB[j] + half * 128 * K + kt * 64,
                       shb + 65536 + (kt & 1) * 32768 + half * 16384 + cj[j] * 16);
    };

    const int swz  = (l15 & 7) << 4;
    const int cb0  = ((q4 * 16) ^ swz);
    const int cb1  = ((64 + q4 * 16) ^ swz);
    const int rowA = (wr * 128 + l15) * 128;
    const int rowB = (wc * 64  + l15) * 128;
    auto RDA = [&](int b, int i, int cb) -> bf16x8 {
        return *(const bf16x8*)(shb + b * 32768 + rowA + i * 2048 + cb);
    };
    auto RDB = [&](int b, int n, int cb) -> bf16x8 {
        return *(const bf16x8*)(shb + 65536 + b * 32768 + rowB + n * 2048 + cb);
    };

    floatx4 acc[8][4];
#pragma unroll
    for (int i = 0; i < 8; i++)
#pragma unroll
        for (int n = 0; n < 4; n++) acc[i][n] = (floatx4){0.f, 0.f, 0.f, 0.f};

    bf16x8 aF0[4][2], aF1[4][2], bF[4][2];

    // ---- prologue ----
    STAGE_A(0, 0); STAGE_B(0, 0); STAGE_A(0, 1); STAGE_B(0, 1);
    STAGE_A(1, 0); STAGE_B(1, 0);
    SCHED_FENCE();
    asm volatile("s_waitcnt vmcnt(4)" ::: "memory");   // kt0 complete
    SCHED_FENCE();
    __builtin_amdgcn_s_barrier();

#pragma unroll 1
    for (int it = 0; it < NIT; ++it) {
        const int kB = 2 * it + 1;
        const bool more = (it < NIT - 1);

        // -------- phase 1: reads buf0 m0-3 (both kh) + B kh0; stage ktB.A1
#pragma unroll
        for (int i = 0; i < 4; i++) { aF0[i][0] = RDA(0, i, cb0); aF0[i][1] = RDA(0, i, cb1); }
#pragma unroll
        for (int n = 0; n < 4; n++) bF[n][0] = RDB(0, n, cb0);
        STAGE_A(kB, 1);
        SCHED_FENCE();
        __builtin_amdgcn_s_barrier();
        asm volatile("s_waitcnt lgkmcnt(0)" ::: "memory");
        SCHED_FENCE();
        __builtin_amdgcn_s_setprio(1);
#pragma unroll
        for (int i = 0; i < 4; i++)
#pragma unroll
            for (int n = 0; n < 4; n++)
                acc[i][n] = __builtin_amdgcn_mfma_f32_16x16x32_bf16(aF0[i][0], bF[n][0], acc[i][n], 0, 0, 0);
        __builtin_amdgcn_s_setprio(0);
        SCHED_FENCE();
        __builtin_amdgcn_s_barrier();

        // -------- phase 2: reads buf0 m4-7 (both kh) + B kh1; stage ktB.B1
#pragma unroll
        for (int i = 0; i < 4; i++) { aF1[i][0] = RDA(0, i + 4, cb0); aF1[i][1] = RDA(0, i + 4, cb1); }
#pragma unroll
        for (int n = 0; n < 4; n++) bF[n][1] = RDB(0, n, cb1);
        STAGE_B(kB, 1);
        SCHED_FENCE();
        __builtin_amdgcn_s_barrier();
        asm volatile("s_waitcnt lgkmcnt(0)" ::: "memory");
        SCHED_FENCE();
        __builtin_amdgcn_s_setprio(1);
#pragma unroll
        for (int i = 0; i < 4; i++)
#pragma unroll
            for (int n = 0; n < 4; n++)
                acc[i][n] = __builtin_amdgcn_mfma_f32_16x16x32_bf16(aF0[i][1], bF[n][1], acc[i][n], 0, 0, 0);
        __builtin_amdgcn_s_setprio(0);
        SCHED_FENCE();
        __builtin_amdgcn_s_barrier();

        // -------- phase 3: buf0 read-free; stage ktA+2.A0
        if (more) STAGE_A(kB + 1, 0);
        SCHED_FENCE();
        __builtin_amdgcn_s_barrier();
        __builtin_amdgcn_s_setprio(1);
#pragma unroll
        for (int i = 0; i < 4; i++)
#pragma unroll
            for (int n = 0; n < 4; n++)
                acc[i + 4][n] = __builtin_amdgcn_mfma_f32_16x16x32_bf16(aF1[i][0], bF[n][0], acc[i + 4][n], 0, 0, 0);
        __builtin_amdgcn_s_setprio(0);
        SCHED_FENCE();
        __builtin_amdgcn_s_barrier();

        // -------- phase 4: stage ktA+2.B0; wait ktB staged
        if (more) STAGE_B(kB + 1, 0);
        if (more) { SCHED_FENCE(); asm volatile("s_waitcnt vmcnt(4)" ::: "memory"); }
        else      { SCHED_FENCE(); asm volatile("s_waitcnt vmcnt(0)" ::: "memory"); }
        SCHED_FENCE();
        __builtin_amdgcn_s_barrier();
        __builtin_amdgcn_s_setprio(1);
#pragma unroll
        for (int i = 0; i < 4; i++)
#pragma unroll
            for (int n = 0; n < 4; n++)
                acc[i + 4][n] = __builtin_amdgcn_mfma_f32_16x16x32_bf16(aF1[i][1], bF[n][1], acc[i + 4][n], 0, 0, 0);
        __builtin_amdgcn_s_setprio(0);
        SCHED_FENCE();
        __builtin_amdgcn_s_barrier();

        // -------- phase 5: reads buf1 m0-3 + B kh0; stage ktA+2.A1
#pragma unroll
        for (int i = 0; i < 4; i++) { aF0[i][0] = RDA(1, i, cb0); aF0[i][1] = RDA(1, i, cb1); }
#pragma unroll
        for (int n = 0; n < 4; n++) bF[n][0] = RDB(1, n, cb0);
        if (more) STAGE_A(kB + 1, 1);
        SCHED_FENCE();
        __builtin_amdgcn_s_barrier();
        asm volatile("s_waitcnt lgkmcnt(0)" ::: "memory");
        SCHED_FENCE();
        __builtin_amdgcn_s_setprio(1);
#pragma unroll
        for (int i = 0; i < 4; i++)
#pragma unroll
            for (int n = 0; n < 4; n++)
                acc[i][n] = __builtin_amdgcn_mfma_f32_16x16x32_bf16(aF0[i][0], bF[n][0], acc[i][n], 0, 0, 0);
        __builtin_amdgcn_s_setprio(0);
        SCHED_FENCE();
        __builtin_amdgcn_s_barrier();

        // -------- phase 6: reads buf1 m4-7 + B kh1; stage ktA+2.B1
#pragma unroll
        for (int i = 0; i < 4; i++) { aF1[i][0] = RDA(1, i + 4, cb0); aF1[i][1] = RDA(1, i + 4, cb1); }
#pragma unroll
        for (int n = 0; n < 4; n++) bF[n][1] = RDB(1, n, cb1);
        if (more) STAGE_B(kB + 1, 1);
        SCHED_FENCE();
        __builtin_amdgcn_s_barrier();
        asm volatile("s_waitcnt lgkmcnt(0)" ::: "memory");
        SCHED_FENCE();
        __builtin_amdgcn_s_setprio(1);
#pragma unroll
        for (int i = 0; i < 4; i++)
#pragma unroll
            for (int n = 0; n < 4; n++)
                acc[i][n] = __builtin_amdgcn_mfma_f32_16x16x32_bf16(aF0[i][1], bF[n][1], acc[i][n], 0, 0, 0);
        __builtin_amdgcn_s_setprio(0);
        SCHED_FENCE();
        __builtin_amdgcn_s_barrier();

        // -------- phase 7: buf1 read-free; stage ktB+2.A0
        if (more) STAGE_A(kB + 2, 0);
        SCHED_FENCE();
        __builtin_amdgcn_s_barrier();
        __builtin_amdgcn_s_setprio(1);
#pragma unroll
        for (int i = 0; i < 4; i++)
#pragma unroll
            for (int n = 0; n < 4; n++)
                acc[i + 4][n] = __builtin_amdgcn_mfma_f32_16x16x32_bf16(aF1[i][0], bF[n][0], acc[i + 4][n], 0, 0, 0);
        __builtin_amdgcn_s_setprio(0);
        SCHED_FENCE();
        __builtin_amdgcn_s_barrier();

        // -------- phase 8: stage ktB+2.B0; wait next ktA staged
        if (more) STAGE_B(kB + 2, 0);
        if (more) { SCHED_FENCE(); asm volatile("s_waitcnt vmcnt(4)" ::: "memory"); }
        SCHED_FENCE();
        __builtin_amdgcn_s_barrier();
        __builtin_amdgcn_s_setprio(1);
#pragma unroll
        for (int i = 0; i < 4; i++)
#pragma unroll
            for (int n = 0; n < 4; n++)
                acc[i + 4][n] = __builtin_amdgcn_mfma_f32_16x16x32_bf16(aF1[i][1], bF[n][1], acc[i + 4][n], 0, 0, 0);
        __builtin_amdgcn_s_setprio(0);
        SCHED_FENCE();
        __builtin_amdgcn_s_barrier();
    }

    // ---- epilogue: repack through LDS (per-wave region), coalesced stores ----
    float* X = (float*)shb + wid * 2176;
#pragma unroll
    for (int cidx = 0; cidx < 4; ++cidx) {
#pragma unroll
        for (int i2 = 0; i2 < 2; ++i2) {
            const int i = cidx * 2 + i2;
#pragma unroll
            for (int n = 0; n < 4; ++n) {
                const int col = n0 + wc * 64 + n * 16 + l15;
                const float bv = bias[col];
                int rc = 0;
                if (EPI == 1) { int h = col / 192; rc = col - h * 192; }
#pragma unroll
                for (int r = 0; r < 4; ++r) {
                    const int lrow = i2 * 16 + q4 * 4 + r;
                    float v = acc[i][n][r] + bv;
                    if (EPI == 1) {
                        const int grow = m0 + wr * 128 + cidx * 32 + lrow;
                        if (rc < 64)        v *= 0.125f;
                        else if (rc < 128)  v += pe[(grow & (SEQ - 1)) * 64 + (rc - 64)];
                    }
                    X[lrow * 68 + n * 16 + l15] = v;
                }
            }
        }
#pragma unroll
        for (int rr = 0; rr < 8; ++rr) {
            const int lr   = rr * 4 + q4;
            const int grow = m0 + wr * 128 + cidx * 32 + lr;
            const float* p = X + lr * 68 + l15 * 4;
            if (EPI == 1) {
                ushort4 o;
                o.x = f2bf(p[0]); o.y = f2bf(p[1]); o.z = f2bf(p[2]); o.w = f2bf(p[3]);
                *(ushort4*)((unsigned short*)Cout + (size_t)grow * N + n0 + wc * 64 + l15 * 4) = o;
            } else {
                float4 o = make_float4(p[0], p[1], p[2], p[3]);
                *(float4*)((float*)Cout + (size_t)grow * N + n0 + wc * 64 + l15 * 4) = o;
            }
        }
    }
}

// ---- per-token across-heads attention: 1 wave per token ----
__global__ __launch_bounds__(256) void k_attn(const unsigned short* __restrict__ qkv,
                                              unsigned short* __restrict__ aout) {
    __shared__ __align__(16) float X4[4][3264];
    __shared__ float S4[4][272];
    int tid = threadIdx.x, wid = tid >> 6, lane = tid & 63;
    int t = blockIdx.x * 4 + wid;

    float* X = X4[wid];
    const unsigned short* src = qkv + (size_t)t * NQKV;

#pragma unroll
    for (int c = 0; c < 6; c++) {
        int ci = c * 64 + lane;
        uint4 u = ((const uint4*)src)[ci];
        int j0 = ci * 8;
        int h  = j0 / 192;
        int rc = j0 - h * 192;
        float* dst = X + h * 204 + rc;
        floatx4 f0 = { bf2f(u.x & 0xffff), bf2f(u.x >> 16), bf2f(u.y & 0xffff), bf2f(u.y >> 16) };
        floatx4 f1 = { bf2f(u.z & 0xffff), bf2f(u.z >> 16), bf2f(u.w & 0xffff), bf2f(u.w >> 16) };
        *(floatx4*)dst       = f0;
        *(floatx4*)(dst + 4) = f1;
    }
    __syncthreads();

    int h  = lane >> 2;
    int g0 = (lane & 3) * 4;
    const float* Q = X + h * 204;
    float s0 = 0.f, s1 = 0.f, s2 = 0.f, s3 = 0.f;
#pragma unroll 8
    for (int d = 0; d < 64; d++) {
        float qd = Q[d];
        s0 += qd * X[(g0 + 0) * 204 + 64 + d];
        s1 += qd * X[(g0 + 1) * 204 + 64 + d];
        s2 += qd * X[(g0 + 2) * 204 + 64 + d];
        s3 += qd * X[(g0 + 3) * 204 + 64 + d];
    }
    float mx = fmaxf(fmaxf(s0, s1), fmaxf(s2, s3));
    mx = fmaxf(mx, __shfl_xor(mx, 1));
    mx = fmaxf(mx, __shfl_xor(mx, 2));
    float e0 = __expf(s0 - mx), e1 = __expf(s1 - mx), e2 = __expf(s2 - mx), e3 = __expf(s3 - mx);
    float sum = e0 + e1 + e2 + e3;
    sum += __shfl_xor(sum, 1);
    sum += __shfl_xor(sum, 2);
    float inv = 1.0f / sum;
    float* Sr = &S4[wid][h * 17];
    Sr[g0 + 0] = e0 * inv; Sr[g0 + 1] = e1 * inv; Sr[g0 + 2] = e2 * inv; Sr[g0 + 3] = e3 * inv;
    __syncthreads();

    int db = lane & 3;
    floatx4 o0 = {0,0,0,0}, o1 = {0,0,0,0}, o2 = {0,0,0,0}, o3 = {0,0,0,0};
    const float* Sh = &S4[wid][h * 17];
#pragma unroll
    for (int g = 0; g < 16; g++) {
        float p = Sh[g];
        const floatx4* Vg = (const floatx4*)(X + g * 204 + 128 + db * 16);
        o0 += Vg[0] * p;
        o1 += Vg[1] * p;
        o2 += Vg[2] * p;
        o3 += Vg[3] * p;
    }
    unsigned int w[8];
    w[0] = (unsigned)f2bf(o0[0]) | ((unsigned)f2bf(o0[1]) << 16);
    w[1] = (unsigned)f2bf(o0[2]) | ((unsigned)f2bf(o0[3]) << 16);
    w[2] = (unsigned)f2bf(o1[0]) | ((unsigned)f2bf(o1[1]) << 16);
    w[3] = (unsigned)f2bf(o1[2]) | ((unsigned)f2bf(o1[3]) << 16);
    w[4] = (unsigned)f2bf(o2[0]) | ((unsigned)f2bf(o2[1]) << 16);
    w[5] = (unsigned)f2bf(o2[2]) | ((unsigned)f2bf(o2[3]) << 16);
    w[6] = (unsigned)f2bf(o3[0]) | ((unsigned)f2bf(o3[1]) << 16);
    w[7] = (unsigned)f2bf(o3[2]) | ((unsigned)f2bf(o3[3]) << 16);
    uint4* dst = (uint4*)&aout[(size_t)t * DM + h * 64 + db * 16];
    dst[0] = make_uint4(w[0], w[1], w[2], w[3]);
    dst[1] = make_uint4(w[4], w[5], w[6], w[7]);
}

extern "C" void kernel_launch(void* const* d_in, const int* in_sizes, int n_in,
                              void* d_out, int out_size, void* d_ws, size_t ws_size,
                              hipStream_t stream) {
    const float* x     = (const float*)d_in[0];
    const float* w_qkv = (const float*)d_in[1];
    const float* b_qkv = (const float*)d_in[2];
    const float* w_out = (const float*)d_in[3];
    const float* b_out = (const float*)d_in[4];
    float* out = (float*)d_out;

    char* ws = (char*)d_ws;
    float*          pe    = (float*)ws;
    unsigned short* wqkvT = (unsigned short*)(ws + (1u << 20));
    unsigned short* woutT = (unsigned short*)(ws + (1u << 20) + 6291456u);
    unsigned short* xbf   = (unsigned short*)(ws + (1u << 20) + 6291456u + 2097152u);
    unsigned short* qkv   = (unsigned short*)(ws + (1u << 20) + 6291456u + 2097152u + 67108864u);
    unsigned short* aout  = xbf;  // x_bf16 dead after GEMM1; reuse for attention output

    // prep
    k_cast_bf16<<<(NTOK * DM / 4 + 255) / 256, 256, 0, stream>>>(x, xbf, NTOK * DM / 4);
    k_transpose_cast<1024, 3072><<<dim3(96, 32), dim3(32, 8), 0, stream>>>(w_qkv, wqkvT);
    k_transpose_cast<1024, 1024><<<dim3(32, 32), dim3(32, 8), 0, stream>>>(w_out, woutT);
    k_pe<<<512, 256, 0, stream>>>(pe);

    // qkv = x @ w_qkv + b_qkv  (8-phase 256x256; fused: q*=1/8, k+=pe, bf16 store)
    k_gemm8<NQKV, 1><<<dim3((NQKV / 256) * (NTOK / 256)), 512, 0, stream>>>(xbf, wqkvT, b_qkv, pe, qkv);

    // per-token across-heads attention
    k_attn<<<NTOK / 4, 256, 0, stream>>>(qkv, aout);

    // out = attn_out @ w_out + b_out (proven 2-phase 128x128, fp32 store)
    k_gemm<DM, 0><<<dim3(DM / 128, NTOK / 128), 256, 0, stream>>>(aout, woutT, b_out, nullptr, out);
}

// Round 3
// 775.955 us; speedup vs baseline: 1.1475x; 1.1475x over previous
//
#include <hip/hip_runtime.h>
#include <hip/hip_bf16.h>
#include <cstdint>
#include <cstddef>

#define NH   16
#define DHD  64
#define DM   1024
#define BSZ  8
#define SEQ  4096
#define NTOK (BSZ*SEQ)      // 32768 tokens
#define NQKV (3*NH*DHD)     // 3072

typedef __attribute__((ext_vector_type(8))) __bf16 bf16x8;
typedef __attribute__((ext_vector_type(4))) float  floatx4;

// ---- helpers ----
static __device__ __forceinline__ unsigned short f2bf(float f) {
    unsigned int u = __float_as_uint(f);
    u += 0x7fffu + ((u >> 16) & 1u);   // RNE
    return (unsigned short)(u >> 16);
}
static __device__ __forceinline__ float bf2f(unsigned int us) {
    return __uint_as_float(us << 16);
}
static __device__ __forceinline__ void load_lds16(const void* g, void* l) {
    __builtin_amdgcn_global_load_lds((__attribute__((address_space(1))) void*)g,
                                     (__attribute__((address_space(3))) void*)l,
                                     16, 0, 0);
}

// ---- cast fp32 -> bf16 (vectorized, exact multiple of 4) ----
__global__ __launch_bounds__(256) void k_cast_bf16(const float* __restrict__ in,
                                                   unsigned short* __restrict__ out, int n4) {
    int i = blockIdx.x * 256 + threadIdx.x;
    if (i >= n4) return;
    float4 v = ((const float4*)in)[i];
    ushort4 o;
    o.x = f2bf(v.x); o.y = f2bf(v.y); o.z = f2bf(v.z); o.w = f2bf(v.w);
    ((ushort4*)out)[i] = o;
}

// ---- transpose + cast: in fp32 [R][C] -> out bf16 [C][R] ----
template<int R, int C>
__global__ __launch_bounds__(256) void k_transpose_cast(const float* __restrict__ in,
                                                        unsigned short* __restrict__ out) {
    __shared__ float tile[32][33];
    int tx = threadIdx.x, ty = threadIdx.y;    // (32, 8)
    int col = blockIdx.x * 32 + tx;
#pragma unroll
    for (int k = 0; k < 4; k++) {
        int row = blockIdx.y * 32 + ty + k * 8;
        tile[ty + k * 8][tx] = in[(size_t)row * C + col];
    }
    __syncthreads();
#pragma unroll
    for (int k = 0; k < 4; k++) {
        int ocol = blockIdx.x * 32 + ty + k * 8;   // original col -> out row
        int orow = blockIdx.y * 32 + tx;           // original row -> out col
        out[(size_t)ocol * R + orow] = f2bf(tile[tx][ty + k * 8]);
    }
}

// ---- positional encoding table fp32 [4096][64] ----
__global__ __launch_bounds__(256) void k_pe(float* __restrict__ pe) {
    int t = blockIdx.x * 256 + threadIdx.x;   // 4096*32
    int l = t >> 5, i = t & 31;
    float dv = expf(-0.14391156831212787f * (float)(2 * i));
    float ang = (float)l * dv;
    pe[l * 64 + 2 * i]     = sinf(ang);
    pe[l * 64 + 2 * i + 1] = cosf(ang);
}

// ============================================================================
// 2-phase 128x128 bf16 GEMM, BK = 64, XOR-swizzled LDS, coalesced epilogue.
//   C[M][N] = A[M][1024] @ BT[N][1024]^T + bias
// vs round-0 k_gemm (370 us GEMM1):
//   - BK 32 -> 64: halves __syncthreads + vmcnt-drain events (the structural
//     ~20% stall of this loop). LDS = As[128][64] + Bs[128][64] = 32 KiB.
//   - XOR swizzle (proven in r1/r2 gemm8): physical 16B-slot s of row r holds
//     logical slot s^(r&7). Staging pre-swizzles the GLOBAL source per lane
//     (global_load_lds writes linearly); ds_read XORs the column. Kills the
//     2.5e7/dispatch bank conflicts of round-0's unswizzled reads.
//   - Epilogue repacks acc through per-wave LDS region -> coalesced
//     ushort4/float4 stores (round-0: 64 scattered 2B stores/lane,
//     WRITE_SIZE 307 MB vs 192 ideal).
// 4 waves as 2(M) x 2(N); per-wave output 64x64 = acc[4][4]; K-step split in
// two kh sub-phases so only 8 fragment regs live (keeps ~3 blocks/CU).
// ============================================================================
template<int N, int EPI>
__global__ __launch_bounds__(256) void k_gemm(const unsigned short* __restrict__ A,
                                              const unsigned short* __restrict__ BT,
                                              const float* __restrict__ bias,
                                              const float* __restrict__ pe,
                                              void* __restrict__ Cout) {
    constexpr int K = 1024;
    __shared__ __align__(16) short lds[16384];   // 32 KiB: As 16 KiB + Bs 16 KiB
    char* shb = (char*)lds;

    const int tid  = threadIdx.x;
    const int lane = tid & 63;
    const int wid  = tid >> 6;
    const int l15  = lane & 15;
    const int q4   = lane >> 4;
    const int m0 = blockIdx.y * 128;
    const int n0 = blockIdx.x * 128;
    const int wr = wid >> 1, wc = wid & 1;

    floatx4 acc[4][4];
#pragma unroll
    for (int i = 0; i < 4; i++)
#pragma unroll
        for (int j = 0; j < 4; j++) acc[i][j] = (floatx4){0.f, 0.f, 0.f, 0.f};

    // ---- staging: per matrix 1024 16B-chunks (128 rows x 8 slots); thread
    // stages 4 chunks per matrix: ci_j = wid*256 + j*64 + lane (j=0..3).
    // For all j: ci&7 = lane&7, rh&7 = (lane>>3)&7 -> same logical slot; the
    // j chunks are +8 rows / +1 KiB LDS apart.
    const int ci0 = wid * 256 + lane;
    const int rh0 = ci0 >> 3;                         // row of chunk 0
    const int sl  = (lane & 7) ^ ((lane >> 3) & 7);   // logical slot (inverse swizzle)
    const unsigned short* srcA = A  + (size_t)(m0 + rh0) * K + sl * 8;
    const unsigned short* srcB = BT + (size_t)(n0 + rh0) * K + sl * 8;
    char* dstA = shb + ci0 * 16;
    char* dstB = shb + 16384 + ci0 * 16;

    // ---- fragment read addressing (swizzled; row stride 128 B) ----
    const int swz  = (l15 & 7) << 4;
    const int cb0  = (q4 * 16) ^ swz;          // kh0 byte col
    const int rowA = (wr * 64 + l15) * 128;    // byte row base, A side
    const int rowB = (wc * 64 + l15) * 128;

    for (int kb = 0; kb < K; kb += 64) {
        __syncthreads();                        // previous reads done
#pragma unroll
        for (int j = 0; j < 4; j++) {
            load_lds16(srcA + kb + j * 8 * K, dstA + j * 1024);
            load_lds16(srcB + kb + j * 8 * K, dstB + j * 1024);
        }
        __syncthreads();                        // staging visible (vmcnt drain)

        bf16x8 aF[4], bF[4];
        // ---- kh0 ----
#pragma unroll
        for (int i = 0; i < 4; i++)
            aF[i] = *(const bf16x8*)(shb + rowA + i * 2048 + cb0);
#pragma unroll
        for (int j = 0; j < 4; j++)
            bF[j] = *(const bf16x8*)(shb + 16384 + rowB + j * 2048 + cb0);
#pragma unroll
        for (int i = 0; i < 4; i++)
#pragma unroll
            for (int j = 0; j < 4; j++)
                acc[i][j] = __builtin_amdgcn_mfma_f32_16x16x32_bf16(aF[i], bF[j], acc[i][j], 0, 0, 0);
        // ---- kh1 ----
#pragma unroll
        for (int i = 0; i < 4; i++)
            aF[i] = *(const bf16x8*)(shb + rowA + i * 2048 + (cb0 ^ 64));
#pragma unroll
        for (int j = 0; j < 4; j++)
            bF[j] = *(const bf16x8*)(shb + 16384 + rowB + j * 2048 + (cb0 ^ 64));
#pragma unroll
        for (int i = 0; i < 4; i++)
#pragma unroll
            for (int j = 0; j < 4; j++)
                acc[i][j] = __builtin_amdgcn_mfma_f32_16x16x32_bf16(aF[i], bF[j], acc[i][j], 0, 0, 0);
    }

    // ---- epilogue: repack through per-wave LDS region, coalesced stores ----
    __syncthreads();                            // all K-loop reads done before reuse
    float* X = (float*)shb + wid * 1088;        // 16 rows x 68 f32 per wave
#pragma unroll
    for (int i = 0; i < 4; ++i) {               // m-frag = 16 rows
#pragma unroll
        for (int n = 0; n < 4; ++n) {
            const int col = n0 + wc * 64 + n * 16 + l15;
            const float bv = bias[col];
            int rc = 0;
            if (EPI == 1) { int h = col / 192; rc = col - h * 192; }
#pragma unroll
            for (int r = 0; r < 4; ++r) {
                const int lrow = q4 * 4 + r;
                float v = acc[i][n][r] + bv;
                if (EPI == 1) {
                    const int grow = m0 + wr * 64 + i * 16 + lrow;
                    if (rc < 64)        v *= 0.125f;                        // q * (1/sqrt(64))
                    else if (rc < 128)  v += pe[(grow & (SEQ - 1)) * 64 + (rc - 64)];
                }
                X[lrow * 68 + n * 16 + l15] = v;
            }
        }
        // wave-local: compiler orders ds_write -> ds_read via lgkmcnt
#pragma unroll
        for (int rr = 0; rr < 4; ++rr) {
            const int lr   = rr * 4 + q4;
            const int grow = m0 + wr * 64 + i * 16 + lr;
            const float* p = X + lr * 68 + l15 * 4;
            if (EPI == 1) {
                ushort4 o;
                o.x = f2bf(p[0]); o.y = f2bf(p[1]); o.z = f2bf(p[2]); o.w = f2bf(p[3]);
                *(ushort4*)((unsigned short*)Cout + (size_t)grow * N + n0 + wc * 64 + l15 * 4) = o;
            } else {
                float4 o = make_float4(p[0], p[1], p[2], p[3]);
                *(float4*)((float*)Cout + (size_t)grow * N + n0 + wc * 64 + l15 * 4) = o;
            }
        }
    }
}

// ---- per-token across-heads attention: 1 wave per token ----
// qkv row layout: head h -> [q(64) | k(64) | v(64)] at col h*192; q pre-scaled, k has pe.
__global__ __launch_bounds__(256) void k_attn(const unsigned short* __restrict__ qkv,
                                              unsigned short* __restrict__ aout) {
    __shared__ __align__(16) float X4[4][3264];   // per-wave: 16 rows, stride 204
    __shared__ float S4[4][272];                  // softmax probs, [16][17]
    int tid = threadIdx.x, wid = tid >> 6, lane = tid & 63;
    int t = blockIdx.x * 4 + wid;

    float* X = X4[wid];
    const unsigned short* src = qkv + (size_t)t * NQKV;

#pragma unroll
    for (int c = 0; c < 6; c++) {
        int ci = c * 64 + lane;
        uint4 u = ((const uint4*)src)[ci];
        int j0 = ci * 8;
        int h  = j0 / 192;
        int rc = j0 - h * 192;
        float* dst = X + h * 204 + rc;
        floatx4 f0 = { bf2f(u.x & 0xffff), bf2f(u.x >> 16), bf2f(u.y & 0xffff), bf2f(u.y >> 16) };
        floatx4 f1 = { bf2f(u.z & 0xffff), bf2f(u.z >> 16), bf2f(u.w & 0xffff), bf2f(u.w >> 16) };
        *(floatx4*)dst       = f0;
        *(floatx4*)(dst + 4) = f1;
    }
    __syncthreads();

    int h  = lane >> 2;
    int g0 = (lane & 3) * 4;
    const float* Q = X + h * 204;
    float s0 = 0.f, s1 = 0.f, s2 = 0.f, s3 = 0.f;
#pragma unroll 8
    for (int d = 0; d < 64; d++) {
        float qd = Q[d];
        s0 += qd * X[(g0 + 0) * 204 + 64 + d];
        s1 += qd * X[(g0 + 1) * 204 + 64 + d];
        s2 += qd * X[(g0 + 2) * 204 + 64 + d];
        s3 += qd * X[(g0 + 3) * 204 + 64 + d];
    }
    float mx = fmaxf(fmaxf(s0, s1), fmaxf(s2, s3));
    mx = fmaxf(mx, __shfl_xor(mx, 1));
    mx = fmaxf(mx, __shfl_xor(mx, 2));
    float e0 = __expf(s0 - mx), e1 = __expf(s1 - mx), e2 = __expf(s2 - mx), e3 = __expf(s3 - mx);
    float sum = e0 + e1 + e2 + e3;
    sum += __shfl_xor(sum, 1);
    sum += __shfl_xor(sum, 2);
    float inv = 1.0f / sum;
    float* Sr = &S4[wid][h * 17];
    Sr[g0 + 0] = e0 * inv; Sr[g0 + 1] = e1 * inv; Sr[g0 + 2] = e2 * inv; Sr[g0 + 3] = e3 * inv;
    __syncthreads();

    int db = lane & 3;
    floatx4 o0 = {0,0,0,0}, o1 = {0,0,0,0}, o2 = {0,0,0,0}, o3 = {0,0,0,0};
    const float* Sh = &S4[wid][h * 17];
#pragma unroll
    for (int g = 0; g < 16; g++) {
        float p = Sh[g];
        const floatx4* Vg = (const floatx4*)(X + g * 204 + 128 + db * 16);
        o0 += Vg[0] * p;
        o1 += Vg[1] * p;
        o2 += Vg[2] * p;
        o3 += Vg[3] * p;
    }
    unsigned int w[8];
    w[0] = (unsigned)f2bf(o0[0]) | ((unsigned)f2bf(o0[1]) << 16);
    w[1] = (unsigned)f2bf(o0[2]) | ((unsigned)f2bf(o0[3]) << 16);
    w[2] = (unsigned)f2bf(o1[0]) | ((unsigned)f2bf(o1[1]) << 16);
    w[3] = (unsigned)f2bf(o1[2]) | ((unsigned)f2bf(o1[3]) << 16);
    w[4] = (unsigned)f2bf(o2[0]) | ((unsigned)f2bf(o2[1]) << 16);
    w[5] = (unsigned)f2bf(o2[2]) | ((unsigned)f2bf(o2[3]) << 16);
    w[6] = (unsigned)f2bf(o3[0]) | ((unsigned)f2bf(o3[1]) << 16);
    w[7] = (unsigned)f2bf(o3[2]) | ((unsigned)f2bf(o3[3]) << 16);
    uint4* dst = (uint4*)&aout[(size_t)t * DM + h * 64 + db * 16];
    dst[0] = make_uint4(w[0], w[1], w[2], w[3]);
    dst[1] = make_uint4(w[4], w[5], w[6], w[7]);
}

extern "C" void kernel_launch(void* const* d_in, const int* in_sizes, int n_in,
                              void* d_out, int out_size, void* d_ws, size_t ws_size,
                              hipStream_t stream) {
    const float* x     = (const float*)d_in[0];
    const float* w_qkv = (const float*)d_in[1];
    const float* b_qkv = (const float*)d_in[2];
    const float* w_out = (const float*)d_in[3];
    const float* b_out = (const float*)d_in[4];
    float* out = (float*)d_out;

    // ws layout (bytes):
    //   pe      fp32 [4096][64]        @ 0          (1 MiB)
    //   wqkvT   bf16 [3072][1024]      @ 1 MiB      (6 MiB)
    //   woutT   bf16 [1024][1024]      @ 7 MiB      (2 MiB)
    //   xbf     bf16 [32768][1024]     @ 9 MiB      (64 MiB)   (reused as attn_out)
    //   qkv     bf16 [32768][3072]     @ 73 MiB     (192 MiB)
    char* ws = (char*)d_ws;
    float*          pe    = (float*)ws;
    unsigned short* wqkvT = (unsigned short*)(ws + (1u << 20));
    unsigned short* woutT = (unsigned short*)(ws + (1u << 20) + 6291456u);
    unsigned short* xbf   = (unsigned short*)(ws + (1u << 20) + 6291456u + 2097152u);
    unsigned short* qkv   = (unsigned short*)(ws + (1u << 20) + 6291456u + 2097152u + 67108864u);
    unsigned short* aout  = xbf;  // x_bf16 dead after GEMM1; reuse for attention output

    // prep
    k_cast_bf16<<<(NTOK * DM / 4 + 255) / 256, 256, 0, stream>>>(x, xbf, NTOK * DM / 4);
    k_transpose_cast<1024, 3072><<<dim3(96, 32), dim3(32, 8), 0, stream>>>(w_qkv, wqkvT);
    k_transpose_cast<1024, 1024><<<dim3(32, 32), dim3(32, 8), 0, stream>>>(w_out, woutT);
    k_pe<<<512, 256, 0, stream>>>(pe);

    // qkv = x @ w_qkv + b_qkv  (fused: q*=1/8, k+=pe, bf16 store)
    k_gemm<NQKV, 1><<<dim3(NQKV / 128, NTOK / 128), 256, 0, stream>>>(xbf, wqkvT, b_qkv, pe, qkv);

    // per-token across-heads attention
    k_attn<<<NTOK / 4, 256, 0, stream>>>(qkv, aout);

    // out = attn_out @ w_out + b_out (fp32 store)
    k_gemm<DM, 0><<<dim3(DM / 128, NTOK / 128), 256, 0, stream>>>(aout, woutT, b_out, nullptr, out);
}

// Round 4
// 705.726 us; speedup vs baseline: 1.2617x; 1.0995x over previous
//
#include <hip/hip_runtime.h>
#include <hip/hip_bf16.h>
#include <cstdint>
#include <cstddef>

#define NH   16
#define DHD  64
#define DM   1024
#define BSZ  8
#define SEQ  4096
#define NTOK (BSZ*SEQ)      // 32768 tokens
#define NQKV (3*NH*DHD)     // 3072

typedef __attribute__((ext_vector_type(8))) __bf16 bf16x8;
typedef __attribute__((ext_vector_type(4))) float  floatx4;

// ---- helpers ----
static __device__ __forceinline__ unsigned short f2bf(float f) {
    unsigned int u = __float_as_uint(f);
    u += 0x7fffu + ((u >> 16) & 1u);   // RNE
    return (unsigned short)(u >> 16);
}
static __device__ __forceinline__ float bf2f(unsigned int us) {
    return __uint_as_float(us << 16);
}
static __device__ __forceinline__ void load_lds16(const void* g, void* l) {
    __builtin_amdgcn_global_load_lds((__attribute__((address_space(1))) void*)g,
                                     (__attribute__((address_space(3))) void*)l,
                                     16, 0, 0);
}

// ---- cast fp32 -> bf16 (vectorized, exact multiple of 4) ----
__global__ __launch_bounds__(256) void k_cast_bf16(const float* __restrict__ in,
                                                   unsigned short* __restrict__ out, int n4) {
    int i = blockIdx.x * 256 + threadIdx.x;
    if (i >= n4) return;
    float4 v = ((const float4*)in)[i];
    ushort4 o;
    o.x = f2bf(v.x); o.y = f2bf(v.y); o.z = f2bf(v.z); o.w = f2bf(v.w);
    ((ushort4*)out)[i] = o;
}

// ---- transpose + cast: in fp32 [R][C] -> out bf16 [C][R] ----
template<int R, int C>
__global__ __launch_bounds__(256) void k_transpose_cast(const float* __restrict__ in,
                                                        unsigned short* __restrict__ out) {
    __shared__ float tile[32][33];
    int tx = threadIdx.x, ty = threadIdx.y;    // (32, 8)
    int col = blockIdx.x * 32 + tx;
#pragma unroll
    for (int k = 0; k < 4; k++) {
        int row = blockIdx.y * 32 + ty + k * 8;
        tile[ty + k * 8][tx] = in[(size_t)row * C + col];
    }
    __syncthreads();
#pragma unroll
    for (int k = 0; k < 4; k++) {
        int ocol = blockIdx.x * 32 + ty + k * 8;   // original col -> out row
        int orow = blockIdx.y * 32 + tx;           // original row -> out col
        out[(size_t)ocol * R + orow] = f2bf(tile[tx][ty + k * 8]);
    }
}

// ---- positional encoding table fp32 [4096][64] ----
__global__ __launch_bounds__(256) void k_pe(float* __restrict__ pe) {
    int t = blockIdx.x * 256 + threadIdx.x;   // 4096*32
    int l = t >> 5, i = t & 31;
    float dv = expf(-0.14391156831212787f * (float)(2 * i));
    float ang = (float)l * dv;
    pe[l * 64 + 2 * i]     = sinf(ang);
    pe[l * 64 + 2 * i + 1] = cosf(ang);
}

// ---- m97-style bf16 GEMM (round-0 champion, 370 us GEMM1 / ~123 us GEMM2) ----
// C[M][N] = A[M][1024] @ BT[N][1024]^T + bias
// EPI==1: qkv epilogue (q *= 0.125, k += pe, store bf16); EPI==0: store fp32
template<int N, int EPI>
__global__ __launch_bounds__(256) void k_gemm(const unsigned short* __restrict__ A,
                                              const unsigned short* __restrict__ BT,
                                              const float* __restrict__ bias,
                                              const float* __restrict__ pe,
                                              void* __restrict__ Cout) {
    constexpr int K = 1024;
    __shared__ __align__(16) short lds[8192];   // As[128][32] + Bs[128][32] bf16
    short* As = lds;
    short* Bs = lds + 4096;

    int tid  = threadIdx.x;
    int lane = tid & 63;
    int wid  = tid >> 6;
    int m0 = blockIdx.y * 128;
    int n0 = blockIdx.x * 128;
    int wr = wid >> 1, wc = wid & 1;
    int l15 = lane & 15;
    int kq  = (lane >> 4) * 8;

    floatx4 acc[4][4];
#pragma unroll
    for (int i = 0; i < 4; i++)
#pragma unroll
        for (int j = 0; j < 4; j++) acc[i][j] = (floatx4){0.f, 0.f, 0.f, 0.f};

    int ci0 = wid * 128 + lane;
    int ci1 = ci0 + 64;
    const unsigned short* pa0 = A  + (size_t)(m0 + (ci0 >> 2)) * K + (ci0 & 3) * 8;
    const unsigned short* pa1 = A  + (size_t)(m0 + (ci1 >> 2)) * K + (ci1 & 3) * 8;
    const unsigned short* pb0 = BT + (size_t)(n0 + (ci0 >> 2)) * K + (ci0 & 3) * 8;
    const unsigned short* pb1 = BT + (size_t)(n0 + (ci1 >> 2)) * K + (ci1 & 3) * 8;
    short* la0 = As + ci0 * 8;
    short* la1 = As + ci1 * 8;
    short* lb0 = Bs + ci0 * 8;
    short* lb1 = Bs + ci1 * 8;

    for (int kb = 0; kb < K; kb += 32) {
        __syncthreads();                       // previous compute done
        load_lds16(pa0 + kb, la0);
        load_lds16(pa1 + kb, la1);
        load_lds16(pb0 + kb, lb0);
        load_lds16(pb1 + kb, lb1);
        __syncthreads();                       // staging visible (vmcnt drain)

        bf16x8 aF[4], bF[4];
#pragma unroll
        for (int i = 0; i < 4; i++)
            aF[i] = *(const bf16x8*)&As[(wr * 64 + i * 16 + l15) * 32 + kq];
#pragma unroll
        for (int j = 0; j < 4; j++)
            bF[j] = *(const bf16x8*)&Bs[(wc * 64 + j * 16 + l15) * 32 + kq];
#pragma unroll
        for (int i = 0; i < 4; i++)
#pragma unroll
            for (int j = 0; j < 4; j++)
                acc[i][j] = __builtin_amdgcn_mfma_f32_16x16x32_bf16(aF[i], bF[j], acc[i][j], 0, 0, 0);
    }

    int rbase = (lane >> 4) * 4;
#pragma unroll
    for (int j = 0; j < 4; j++) {
        int col = n0 + wc * 64 + j * 16 + l15;
        float bv = bias[col];
        int h = 0, rc = 0;
        if (EPI == 1) { h = col / 192; rc = col - h * 192; }
#pragma unroll
        for (int i = 0; i < 4; i++) {
#pragma unroll
            for (int r = 0; r < 4; r++) {
                int row = m0 + wr * 64 + i * 16 + rbase + r;
                float v = acc[i][j][r] + bv;
                if (EPI == 1) {
                    if (rc < 64)        v *= 0.125f;                       // q pre-scale (1/sqrt(64))
                    else if (rc < 128)  v += pe[(row & (SEQ - 1)) * 64 + (rc - 64)]; // k + pos_enc
                    ((unsigned short*)Cout)[(size_t)row * N + col] = f2bf(v);
                } else {
                    ((float*)Cout)[(size_t)row * N + col] = v;
                }
            }
        }
    }
}

// ============================================================================
// MFMA per-token across-heads attention: 1 wave per token, no cross-wave comm.
// qkv row layout per token: head h -> [q(64) | k(64) | v(64)] at col h*192;
// q pre-scaled by 1/8, k has pe added (both fused in GEMM1's epilogue).
//
// Scores: S[h][g] = q_h . k_g via 2x mfma_f32_16x16x32_bf16:
//   A-frag = Q[l15][q4*8 + 0..7] (+32 for second MFMA), B-frag = K likewise --
//   exactly the (row = lane&15, k = (lane>>4)*8) addressing verified by k_gemm.
//   D layout: col g = lane&15, row h = (lane>>4)*4 + r  (verified by k_gemm).
// Softmax over g: per-r shfl_xor(1,2,4,8) across the 16 l15 lanes; P -> bf16
//   -> tiny per-wave LDS [16][16] redistribute (transpose across lanes).
// PV: out[h][d] = sum_g P[h][g] V[g][d] via 4x mfma_16x16x32 (one per 16-wide
//   d-block), K=32 zero-padded: B-frag elems are V[g = q4*8+e][d] gathered
//   from a per-wave LDS V buffer (row stride 72 bf16); q4>=2 frags are zero
//   (g>=16 doesn't exist), which zeroes the pad product regardless of A.
// Output repacked through the (dead) V buffer -> coalesced 16B stores.
// LDS: 2304 + 512 B per wave = 11.3 KB per 256-block -> high occupancy.
// ============================================================================
__global__ __launch_bounds__(256) void k_attn(const unsigned short* __restrict__ qkv,
                                              unsigned short* __restrict__ aout) {
    __shared__ __align__(16) unsigned short VB[4][16 * 72];  // V rows, stride 72
    __shared__ __align__(16) unsigned short PB[4][16 * 16];  // P[h][g] bf16
    const int tid = threadIdx.x, wid = tid >> 6, lane = tid & 63;
    const int l15 = lane & 15, q4 = lane >> 4;
    const int t = blockIdx.x * 4 + wid;
    const unsigned short* src = qkv + (size_t)t * NQKV;

    unsigned short* vb = VB[wid];
    unsigned short* pb = PB[wid];

    // ---- stage V rows -> LDS (lane covers quarter-row: g = lane>>2, seg = lane&3)
    {
        const int g = lane >> 2, seg = lane & 3;
        const unsigned short* vsrc = src + g * 192 + 128 + seg * 16;
        uint4 v0 = *(const uint4*)(vsrc);
        uint4 v1 = *(const uint4*)(vsrc + 8);
        *(uint4*)(vb + g * 72 + seg * 16)     = v0;
        *(uint4*)(vb + g * 72 + seg * 16 + 8) = v1;
    }

    // ---- Q,K fragments straight from global (row h=l15, k = q4*8 (+32)) ----
    bf16x8 qf0 = *(const bf16x8*)(src + l15 * 192 +       q4 * 8);
    bf16x8 qf1 = *(const bf16x8*)(src + l15 * 192 + 32  + q4 * 8);
    bf16x8 kf0 = *(const bf16x8*)(src + l15 * 192 + 64  + q4 * 8);
    bf16x8 kf1 = *(const bf16x8*)(src + l15 * 192 + 96  + q4 * 8);

    floatx4 s = (floatx4){0.f, 0.f, 0.f, 0.f};
    s = __builtin_amdgcn_mfma_f32_16x16x32_bf16(qf0, kf0, s, 0, 0, 0);
    s = __builtin_amdgcn_mfma_f32_16x16x32_bf16(qf1, kf1, s, 0, 0, 0);
    // s[r] = S[h = q4*4 + r][g = l15]

    // ---- softmax over g (across the 16 l15 lanes), one row per (q4, r) ----
#pragma unroll
    for (int r = 0; r < 4; r++) {
        float v = s[r];
        float mx = v;
        mx = fmaxf(mx, __shfl_xor(mx, 1));
        mx = fmaxf(mx, __shfl_xor(mx, 2));
        mx = fmaxf(mx, __shfl_xor(mx, 4));
        mx = fmaxf(mx, __shfl_xor(mx, 8));
        float e = __expf(v - mx);
        float sm = e;
        sm += __shfl_xor(sm, 1);
        sm += __shfl_xor(sm, 2);
        sm += __shfl_xor(sm, 4);
        sm += __shfl_xor(sm, 8);
        float p = e * (1.0f / sm);
        pb[(q4 * 4 + r) * 16 + l15] = f2bf(p);   // P[h][g]
    }

    // ---- PV: A = P rows (l15), B = V columns; K=32 with zero pad ----
    bf16x8 pA = *(const bf16x8*)(pb + l15 * 16 + (q4 & 1) * 8);  // q4>=2: value irrelevant (B=0)

    union VFrag { bf16x8 v; unsigned short u[8]; };
    floatx4 o[4];
#pragma unroll
    for (int db = 0; db < 4; db++) o[db] = (floatx4){0.f, 0.f, 0.f, 0.f};

#pragma unroll
    for (int db = 0; db < 4; db++) {
        VFrag vf;
#pragma unroll
        for (int e = 0; e < 8; e++) vf.u[e] = 0;
        if (q4 < 2) {
#pragma unroll
            for (int e = 0; e < 8; e++)
                vf.u[e] = vb[(q4 * 8 + e) * 72 + db * 16 + l15];   // V[g][d]
        }
        o[db] = __builtin_amdgcn_mfma_f32_16x16x32_bf16(pA, vf.v, o[db], 0, 0, 0);
    }
    // o[db][r] = out[h = q4*4 + r][d = db*16 + l15]

    // ---- repack through LDS (reuse vb; wave-local ordering is in-order) ----
#pragma unroll
    for (int db = 0; db < 4; db++)
#pragma unroll
        for (int r = 0; r < 4; r++)
            vb[(q4 * 4 + r) * 72 + db * 16 + l15] = f2bf(o[db][r]);

    {
        const int row = lane >> 2, seg = lane & 3;   // lane covers 16 elems
        uint4 w0 = *(const uint4*)(vb + row * 72 + seg * 16);
        uint4 w1 = *(const uint4*)(vb + row * 72 + seg * 16 + 8);
        uint4* dst = (uint4*)&aout[(size_t)t * DM + row * 64 + seg * 16];
        dst[0] = w0;
        dst[1] = w1;
    }
}

extern "C" void kernel_launch(void* const* d_in, const int* in_sizes, int n_in,
                              void* d_out, int out_size, void* d_ws, size_t ws_size,
                              hipStream_t stream) {
    const float* x     = (const float*)d_in[0];
    const float* w_qkv = (const float*)d_in[1];
    const float* b_qkv = (const float*)d_in[2];
    const float* w_out = (const float*)d_in[3];
    const float* b_out = (const float*)d_in[4];
    float* out = (float*)d_out;

    // ws layout (bytes):
    //   pe      fp32 [4096][64]        @ 0          (1 MiB)
    //   wqkvT   bf16 [3072][1024]      @ 1 MiB      (6 MiB)
    //   woutT   bf16 [1024][1024]      @ 7 MiB      (2 MiB)
    //   xbf     bf16 [32768][1024]     @ 9 MiB      (64 MiB)   (reused as attn_out)
    //   qkv     bf16 [32768][3072]     @ 73 MiB     (192 MiB)
    char* ws = (char*)d_ws;
    float*          pe    = (float*)ws;
    unsigned short* wqkvT = (unsigned short*)(ws + (1u << 20));
    unsigned short* woutT = (unsigned short*)(ws + (1u << 20) + 6291456u);
    unsigned short* xbf   = (unsigned short*)(ws + (1u << 20) + 6291456u + 2097152u);
    unsigned short* qkv   = (unsigned short*)(ws + (1u << 20) + 6291456u + 2097152u + 67108864u);
    unsigned short* aout  = xbf;  // x_bf16 dead after GEMM1; reuse for attention output

    // prep
    k_cast_bf16<<<(NTOK * DM / 4 + 255) / 256, 256, 0, stream>>>(x, xbf, NTOK * DM / 4);
    k_transpose_cast<1024, 3072><<<dim3(96, 32), dim3(32, 8), 0, stream>>>(w_qkv, wqkvT);
    k_transpose_cast<1024, 1024><<<dim3(32, 32), dim3(32, 8), 0, stream>>>(w_out, woutT);
    k_pe<<<512, 256, 0, stream>>>(pe);

    // qkv = x @ w_qkv + b_qkv  (fused: q*=1/8, k+=pe, bf16 store)
    k_gemm<NQKV, 1><<<dim3(NQKV / 128, NTOK / 128), 256, 0, stream>>>(xbf, wqkvT, b_qkv, pe, qkv);

    // per-token across-heads attention (MFMA, 1 wave/token)
    k_attn<<<NTOK / 4, 256, 0, stream>>>(qkv, aout);

    // out = attn_out @ w_out + b_out (fp32 store)
    k_gemm<DM, 0><<<dim3(DM / 128, NTOK / 128), 256, 0, stream>>>(aout, woutT, b_out, nullptr, out);
}

// Round 6
// 694.099 us; speedup vs baseline: 1.2828x; 1.0168x over previous
//
#include <hip/hip_runtime.h>
#include <hip/hip_bf16.h>
#include <cstdint>
#include <cstddef>

#define NH   16
#define DHD  64
#define DM   1024
#define BSZ  8
#define SEQ  4096
#define NTOK (BSZ*SEQ)      // 32768 tokens
#define NQKV (3*NH*DHD)     // 3072

typedef __attribute__((ext_vector_type(8))) __bf16 bf16x8;
typedef __attribute__((ext_vector_type(4))) float  floatx4;

// ---- helpers ----
static __device__ __forceinline__ unsigned short f2bf(float f) {
    unsigned int u = __float_as_uint(f);
    u += 0x7fffu + ((u >> 16) & 1u);   // RNE
    return (unsigned short)(u >> 16);
}
static __device__ __forceinline__ float bf2f(unsigned int us) {
    return __uint_as_float(us << 16);
}
static __device__ __forceinline__ void load_lds16(const void* g, void* l) {
    __builtin_amdgcn_global_load_lds((__attribute__((address_space(1))) void*)g,
                                     (__attribute__((address_space(3))) void*)l,
                                     16, 0, 0);
}

// ---- cast fp32 -> bf16 (vectorized, exact multiple of 4) ----
__global__ __launch_bounds__(256) void k_cast_bf16(const float* __restrict__ in,
                                                   unsigned short* __restrict__ out, int n4) {
    int i = blockIdx.x * 256 + threadIdx.x;
    if (i >= n4) return;
    float4 v = ((const float4*)in)[i];
    ushort4 o;
    o.x = f2bf(v.x); o.y = f2bf(v.y); o.z = f2bf(v.z); o.w = f2bf(v.w);
    ((ushort4*)out)[i] = o;
}

// ---- transpose + cast: in fp32 [R][C] -> out bf16 [C][R] ----
template<int R, int C>
__global__ __launch_bounds__(256) void k_transpose_cast(const float* __restrict__ in,
                                                        unsigned short* __restrict__ out) {
    __shared__ float tile[32][33];
    int tx = threadIdx.x, ty = threadIdx.y;    // (32, 8)
    int col = blockIdx.x * 32 + tx;
#pragma unroll
    for (int k = 0; k < 4; k++) {
        int row = blockIdx.y * 32 + ty + k * 8;
        tile[ty + k * 8][tx] = in[(size_t)row * C + col];
    }
    __syncthreads();
#pragma unroll
    for (int k = 0; k < 4; k++) {
        int ocol = blockIdx.x * 32 + ty + k * 8;   // original col -> out row
        int orow = blockIdx.y * 32 + tx;           // original row -> out col
        out[(size_t)ocol * R + orow] = f2bf(tile[tx][ty + k * 8]);
    }
}

// ---- positional encoding table fp32 [4096][64] ----
__global__ __launch_bounds__(256) void k_pe(float* __restrict__ pe) {
    int t = blockIdx.x * 256 + threadIdx.x;   // 4096*32
    int l = t >> 5, i = t & 31;
    float dv = expf(-0.14391156831212787f * (float)(2 * i));
    float ang = (float)l * dv;
    pe[l * 64 + 2 * i]     = sinf(ang);
    pe[l * 64 + 2 * i + 1] = cosf(ang);
}

// ---- m97-style bf16 GEMM (round-0 champion) + XCD-supertile remap ----
// C[M][N] = A[M][1024] @ BT[N][1024]^T + bias
// EPI==1: qkv epilogue (q *= 0.125, k += pe, store bf16); EPI==0: store fp32
//
// ROUND-5/6 CHANGE (the only one vs round-4): block remap so that all N/128
// n-blocks of a given m-row share the same (gid & 7) -> land on the SAME XCD
// (round-robin dispatch), temporally adjacent (ids step 8). The A-tile
// (256 KB) is then fetched into ONE XCD's L2 once instead of by all 8 XCDs
// (G1 FETCH was 320 MB vs 70 MB ideal -- A re-fetch across per-XCD L2s is
// the excess). Remap is bijective: m-block counts (256) divisible by 8.
template<int N, int EPI>
__global__ __launch_bounds__(256) void k_gemm(const unsigned short* __restrict__ A,
                                              const unsigned short* __restrict__ BT,
                                              const float* __restrict__ bias,
                                              const float* __restrict__ pe,
                                              void* __restrict__ Cout) {
    constexpr int K   = 1024;
    constexpr int NBX = N / 128;
    __shared__ __align__(16) short lds[8192];   // As[128][32] + Bs[128][32] bf16
    short* As = lds;
    short* Bs = lds + 4096;

    int tid  = threadIdx.x;
    int lane = tid & 63;
    int wid  = tid >> 6;

    // XCD-supertile remap: gid -> (xcd = gid&7 fastest, then n, then m_sup).
    // m_idx = m_sup*8 + xcd  =>  all n-blocks of m_idx have the same gid&7.
    int gid   = blockIdx.y * NBX + blockIdx.x;
    int xcd   = gid & 7;
    int rest  = gid >> 3;
    int n_idx = rest % NBX;
    int m_sup = rest / NBX;
    int m0 = (m_sup * 8 + xcd) * 128;
    int n0 = n_idx * 128;

    int wr = wid >> 1, wc = wid & 1;
    int l15 = lane & 15;
    int kq  = (lane >> 4) * 8;

    floatx4 acc[4][4];
#pragma unroll
    for (int i = 0; i < 4; i++)
#pragma unroll
        for (int j = 0; j < 4; j++) acc[i][j] = (floatx4){0.f, 0.f, 0.f, 0.f};

    int ci0 = wid * 128 + lane;
    int ci1 = ci0 + 64;
    const unsigned short* pa0 = A  + (size_t)(m0 + (ci0 >> 2)) * K + (ci0 & 3) * 8;
    const unsigned short* pa1 = A  + (size_t)(m0 + (ci1 >> 2)) * K + (ci1 & 3) * 8;
    const unsigned short* pb0 = BT + (size_t)(n0 + (ci0 >> 2)) * K + (ci0 & 3) * 8;
    const unsigned short* pb1 = BT + (size_t)(n0 + (ci1 >> 2)) * K + (ci1 & 3) * 8;
    short* la0 = As + ci0 * 8;
    short* la1 = As + ci1 * 8;
    short* lb0 = Bs + ci0 * 8;
    short* lb1 = Bs + ci1 * 8;

    for (int kb = 0; kb < K; kb += 32) {
        __syncthreads();                       // previous compute done
        load_lds16(pa0 + kb, la0);
        load_lds16(pa1 + kb, la1);
        load_lds16(pb0 + kb, lb0);
        load_lds16(pb1 + kb, lb1);
        __syncthreads();                       // staging visible (vmcnt drain)

        bf16x8 aF[4], bF[4];
#pragma unroll
        for (int i = 0; i < 4; i++)
            aF[i] = *(const bf16x8*)&As[(wr * 64 + i * 16 + l15) * 32 + kq];
#pragma unroll
        for (int j = 0; j < 4; j++)
            bF[j] = *(const bf16x8*)&Bs[(wc * 64 + j * 16 + l15) * 32 + kq];
#pragma unroll
        for (int i = 0; i < 4; i++)
#pragma unroll
            for (int j = 0; j < 4; j++)
                acc[i][j] = __builtin_amdgcn_mfma_f32_16x16x32_bf16(aF[i], bF[j], acc[i][j], 0, 0, 0);
    }

    int rbase = (lane >> 4) * 4;
#pragma unroll
    for (int j = 0; j < 4; j++) {
        int col = n0 + wc * 64 + j * 16 + l15;
        float bv = bias[col];
        int h = 0, rc = 0;
        if (EPI == 1) { h = col / 192; rc = col - h * 192; }
#pragma unroll
        for (int i = 0; i < 4; i++) {
#pragma unroll
            for (int r = 0; r < 4; r++) {
                int row = m0 + wr * 64 + i * 16 + rbase + r;
                float v = acc[i][j][r] + bv;
                if (EPI == 1) {
                    if (rc < 64)        v *= 0.125f;                       // q pre-scale (1/sqrt(64))
                    else if (rc < 128)  v += pe[(row & (SEQ - 1)) * 64 + (rc - 64)]; // k + pos_enc
                    ((unsigned short*)Cout)[(size_t)row * N + col] = f2bf(v);
                } else {
                    ((float*)Cout)[(size_t)row * N + col] = v;
                }
            }
        }
    }
}

// ============================================================================
// MFMA per-token across-heads attention: 1 wave per token (round-4 version).
// ============================================================================
__global__ __launch_bounds__(256) void k_attn(const unsigned short* __restrict__ qkv,
                                              unsigned short* __restrict__ aout) {
    __shared__ __align__(16) unsigned short VB[4][16 * 72];  // V rows, stride 72
    __shared__ __align__(16) unsigned short PB[4][16 * 16];  // P[h][g] bf16
    const int tid = threadIdx.x, wid = tid >> 6, lane = tid & 63;
    const int l15 = lane & 15, q4 = lane >> 4;
    const int t = blockIdx.x * 4 + wid;
    const unsigned short* src = qkv + (size_t)t * NQKV;

    unsigned short* vb = VB[wid];
    unsigned short* pb = PB[wid];

    // ---- stage V rows -> LDS (lane covers quarter-row: g = lane>>2, seg = lane&3)
    {
        const int g = lane >> 2, seg = lane & 3;
        const unsigned short* vsrc = src + g * 192 + 128 + seg * 16;
        uint4 v0 = *(const uint4*)(vsrc);
        uint4 v1 = *(const uint4*)(vsrc + 8);
        *(uint4*)(vb + g * 72 + seg * 16)     = v0;
        *(uint4*)(vb + g * 72 + seg * 16 + 8) = v1;
    }

    // ---- Q,K fragments straight from global (row h=l15, k = q4*8 (+32)) ----
    bf16x8 qf0 = *(const bf16x8*)(src + l15 * 192 +       q4 * 8);
    bf16x8 qf1 = *(const bf16x8*)(src + l15 * 192 + 32  + q4 * 8);
    bf16x8 kf0 = *(const bf16x8*)(src + l15 * 192 + 64  + q4 * 8);
    bf16x8 kf1 = *(const bf16x8*)(src + l15 * 192 + 96  + q4 * 8);

    floatx4 s = (floatx4){0.f, 0.f, 0.f, 0.f};
    s = __builtin_amdgcn_mfma_f32_16x16x32_bf16(qf0, kf0, s, 0, 0, 0);
    s = __builtin_amdgcn_mfma_f32_16x16x32_bf16(qf1, kf1, s, 0, 0, 0);
    // s[r] = S[h = q4*4 + r][g = l15]

    // ---- softmax over g (across the 16 l15 lanes), one row per (q4, r) ----
#pragma unroll
    for (int r = 0; r < 4; r++) {
        float v = s[r];
        float mx = v;
        mx = fmaxf(mx, __shfl_xor(mx, 1));
        mx = fmaxf(mx, __shfl_xor(mx, 2));
        mx = fmaxf(mx, __shfl_xor(mx, 4));
        mx = fmaxf(mx, __shfl_xor(mx, 8));
        float e = __expf(v - mx);
        float sm = e;
        sm += __shfl_xor(sm, 1);
        sm += __shfl_xor(sm, 2);
        sm += __shfl_xor(sm, 4);
        sm += __shfl_xor(sm, 8);
        float p = e * (1.0f / sm);
        pb[(q4 * 4 + r) * 16 + l15] = f2bf(p);   // P[h][g]
    }

    // ---- PV: A = P rows (l15), B = V columns; K=32 with zero pad ----
    bf16x8 pA = *(const bf16x8*)(pb + l15 * 16 + (q4 & 1) * 8);  // q4>=2: value irrelevant (B=0)

    union VFrag { bf16x8 v; unsigned short u[8]; };
    floatx4 o[4];
#pragma unroll
    for (int db = 0; db < 4; db++) o[db] = (floatx4){0.f, 0.f, 0.f, 0.f};

#pragma unroll
    for (int db = 0; db < 4; db++) {
        VFrag vf;
#pragma unroll
        for (int e = 0; e < 8; e++) vf.u[e] = 0;
        if (q4 < 2) {
#pragma unroll
            for (int e = 0; e < 8; e++)
                vf.u[e] = vb[(q4 * 8 + e) * 72 + db * 16 + l15];   // V[g][d]
        }
        o[db] = __builtin_amdgcn_mfma_f32_16x16x32_bf16(pA, vf.v, o[db], 0, 0, 0);
    }
    // o[db][r] = out[h = q4*4 + r][d = db*16 + l15]

    // ---- repack through LDS (reuse vb; wave-local ordering is in-order) ----
#pragma unroll
    for (int db = 0; db < 4; db++)
#pragma unroll
        for (int r = 0; r < 4; r++)
            vb[(q4 * 4 + r) * 72 + db * 16 + l15] = f2bf(o[db][r]);

    {
        const int row = lane >> 2, seg = lane & 3;   // lane covers 16 elems
        uint4 w0 = *(const uint4*)(vb + row * 72 + seg * 16);
        uint4 w1 = *(const uint4*)(vb + row * 72 + seg * 16 + 8);
        uint4* dst = (uint4*)&aout[(size_t)t * DM + row * 64 + seg * 16];
        dst[0] = w0;
        dst[1] = w1;
    }
}

extern "C" void kernel_launch(void* const* d_in, const int* in_sizes, int n_in,
                              void* d_out, int out_size, void* d_ws, size_t ws_size,
                              hipStream_t stream) {
    const float* x     = (const float*)d_in[0];
    const float* w_qkv = (const float*)d_in[1];
    const float* b_qkv = (const float*)d_in[2];
    const float* w_out = (const float*)d_in[3];
    const float* b_out = (const float*)d_in[4];
    float* out = (float*)d_out;

    // ws layout (bytes):
    //   pe      fp32 [4096][64]        @ 0          (1 MiB)
    //   wqkvT   bf16 [3072][1024]      @ 1 MiB      (6 MiB)
    //   woutT   bf16 [1024][1024]      @ 7 MiB      (2 MiB)
    //   xbf     bf16 [32768][1024]     @ 9 MiB      (64 MiB)   (reused as attn_out)
    //   qkv     bf16 [32768][3072]     @ 73 MiB     (192 MiB)
    char* ws = (char*)d_ws;
    float*          pe    = (float*)ws;
    unsigned short* wqkvT = (unsigned short*)(ws + (1u << 20));
    unsigned short* woutT = (unsigned short*)(ws + (1u << 20) + 6291456u);
    unsigned short* xbf   = (unsigned short*)(ws + (1u << 20) + 6291456u + 2097152u);
    unsigned short* qkv   = (unsigned short*)(ws + (1u << 20) + 6291456u + 2097152u + 67108864u);
    unsigned short* aout  = xbf;  // x_bf16 dead after GEMM1; reuse for attention output

    // prep
    k_cast_bf16<<<(NTOK * DM / 4 + 255) / 256, 256, 0, stream>>>(x, xbf, NTOK * DM / 4);
    k_transpose_cast<1024, 3072><<<dim3(96, 32), dim3(32, 8), 0, stream>>>(w_qkv, wqkvT);
    k_transpose_cast<1024, 1024><<<dim3(32, 32), dim3(32, 8), 0, stream>>>(w_out, woutT);
    k_pe<<<512, 256, 0, stream>>>(pe);

    // qkv = x @ w_qkv + b_qkv  (fused: q*=1/8, k+=pe, bf16 store)
    k_gemm<NQKV, 1><<<dim3(NQKV / 128, NTOK / 128), 256, 0, stream>>>(xbf, wqkvT, b_qkv, pe, qkv);

    // per-token across-heads attention (MFMA, 1 wave/token)
    k_attn<<<NTOK / 4, 256, 0, stream>>>(qkv, aout);

    // out = attn_out @ w_out + b_out (fp32 store)
    k_gemm<DM, 0><<<dim3(DM / 128, NTOK / 128), 256, 0, stream>>>(aout, woutT, b_out, nullptr, out);
}